// Round 5
// baseline (130.317 us; speedup 1.0000x reference)
//
#include <hip/hip_runtime.h>
#include <hip/hip_bf16.h>
#include <cstdint>

// Problem constants (fixed by reference)
#define SEQ   2048
#define CH    1024
#define NHEAD 16
#define KSZ   7
#define NCOL  112      // NHEAD * KSZ
#define PADW  3        // KSZ/2

#define NTHREADS 256
#define NKSTEP   32    // CH / 32 (K-steps of the 16x16x32 MFMA)
#define BM       8     // conv rows per block -> 1024 blocks (4/CU)
#define LDK_STR  113   // LDS stride (floats), round-2 proven

#define WS_FRAG_BYTES (NKSTEP * 7 * 64 * 16)   // 229,376 B of pre-packed B-frags

typedef __bf16 v8bf __attribute__((ext_vector_type(8)));
typedef float  v4f  __attribute__((ext_vector_type(4)));

// ---------------------------------------------------------------------------
// K1: W_pred fp32 [1024][112] -> bf16 packed in MFMA B-frag order:
// ws[((s*7 + t)*64 + lane)*8 + j] = W[k = s*32 + (lane>>4)*8 + j][n = t*16 + (lane&15)]
// (unchanged, round-2/3 proven)
// ---------------------------------------------------------------------------
__global__ __launch_bounds__(256)
void prep_w(const float* __restrict__ Wp, __bf16* __restrict__ wsB) {
    const int g  = blockIdx.x * 256 + threadIdx.x;   // 0..114687
    const int j  = g & 7;
    const int l  = (g >> 3) & 63;
    const int st = g >> 9;            // s*7 + t
    const int s  = st / 7;
    const int t  = st - s * 7;
    const int k  = s * 32 + (l >> 4) * 8 + j;
    const int n  = t * 16 + (l & 15);
    wsB[g] = (__bf16)Wp[k * NCOL + n];
}

// ---------------------------------------------------------------------------
// Fused kernel: per block, 8 seq rows of one batch; 1024 blocks -> 4/CU.
//
// Phase 1 (GEMM): round-2-proven M=16 MFMA K-loop, EXCEPT the A-row index is
//   s0 + (lm & 7): MFMA rows 8..15 duplicate rows 0..7 (no OOB, no branch).
//   Epilogue is round 2's verbatim: all quads scatter C rows 0..15 to a
//   16-row ldsK (stride 113); conv reads only rows 0..7.
// Phase 2 (conv): round-3-proven BM=8 streaming conv, win[14] preloaded
//   before the single barrier, nontemporal stores.
// ---------------------------------------------------------------------------
template <bool PRE>
__global__ __launch_bounds__(NTHREADS, 2)
void dynconv_fused(const float* __restrict__ x,
                   const float* __restrict__ Wp,
                   const float* __restrict__ bp,
                   const __bf16* __restrict__ wsB,
                   float* __restrict__ out)
{
    __shared__ float ldsK[16 * LDK_STR];   // 7,232 B (16 rows; conv uses 0..7)

    const int tid  = threadIdx.x;
    const int bb   = blockIdx.x;          // 0..1023
    const int b    = bb >> 8;             // 256 blocks per batch
    const int s0   = (bb & 255) << 3;     // starting sequence row

    const int wave = tid >> 6;
    const int lane = tid & 63;
    const int lq   = lane >> 4;           // quad 0..3
    const int lm   = lane & 15;

    const float* xbase = x + (size_t)b * SEQ * CH;

    // ---- Phase 1: GEMM ----
    // Wave w owns n-tiles {2w, 2w+1}; wave 3 duplicates tile 6 (benign).
    const int tile0 = wave * 2;
    const int tile1 = (wave < 3) ? wave * 2 + 1 : 6;

    v4f acc0 = (v4f){0.f, 0.f, 0.f, 0.f};
    v4f acc1 = (v4f){0.f, 0.f, 0.f, 0.f};

    // A-frag: lane (lq,lm) covers x[row = s0 + (lm&7)][k = s*32 + lq*8 .. +7]
    // (rows 8..15 duplicate rows 0..7; their C rows are discarded)
    const float* arow = xbase + (size_t)(s0 + (lm & 7)) * CH + lq * 8;

    #pragma unroll 8
    for (int s = 0; s < NKSTEP; ++s) {
        const float* p = arow + s * 32;
        const v4f v0 = *(const v4f*)p;
        const v4f v1 = *(const v4f*)(p + 4);
        v8bf af;
        af[0] = (__bf16)v0.x; af[1] = (__bf16)v0.y;
        af[2] = (__bf16)v0.z; af[3] = (__bf16)v0.w;
        af[4] = (__bf16)v1.x; af[5] = (__bf16)v1.y;
        af[6] = (__bf16)v1.z; af[7] = (__bf16)v1.w;

        v8bf bf0, bf1;
        if (PRE) {
            bf0 = *(const v8bf*)&wsB[(size_t)((s * 7 + tile0) * 64 + lane) * 8];
            bf1 = *(const v8bf*)&wsB[(size_t)((s * 7 + tile1) * 64 + lane) * 8];
        } else {
            #pragma unroll
            for (int j = 0; j < 8; ++j) {
                const int k = s * 32 + lq * 8 + j;
                bf0[j] = (__bf16)Wp[k * NCOL + tile0 * 16 + lm];
                bf1[j] = (__bf16)Wp[k * NCOL + tile1 * 16 + lm];
            }
        }
        acc0 = __builtin_amdgcn_mfma_f32_16x16x32_bf16(af, bf0, acc0, 0, 0, 0);
        acc1 = __builtin_amdgcn_mfma_f32_16x16x32_bf16(af, bf1, acc1, 0, 0, 0);
    }

    // Epilogue (round-2 verbatim): bias + scatter all 16 C rows to ldsK.
    // C/D layout: col = lane&15, row = (lane>>4)*4 + reg  [m89/m91 verified]
    {
        const int ct0 = tile0 * 16 + lm;
        const float bias0 = bp[ct0];
        #pragma unroll
        for (int r = 0; r < 4; ++r)
            ldsK[(lq * 4 + r) * LDK_STR + ct0] = acc0[r] + bias0;
        if (wave < 3) {
            const int ct1 = tile1 * 16 + lm;
            const float bias1 = bp[ct1];
            #pragma unroll
            for (int r = 0; r < 4; ++r)
                ldsK[(lq * 4 + r) * LDK_STR + ct1] = acc1[r] + bias1;
        }
    }

    // ---- Phase 2 window preload (round-3-proven pattern) ----
    const int h  = tid >> 4;
    const int c4 = tid << 2;
    const float* xb = xbase + c4;

    v4f win[BM + 6];
    #pragma unroll
    for (int i = 0; i < BM + 6; ++i) {
        const int sg = s0 - PADW + i;
        win[i] = (sg >= 0 && sg < SEQ) ? *(const v4f*)(xb + (size_t)sg * CH)
                                       : (v4f){0.f, 0.f, 0.f, 0.f};
    }

    __syncthreads();

    // ---- Phase 2: dynamic conv (rows 0..7 of ldsK) ----
    float* ob = out + ((size_t)b * SEQ + s0) * CH + c4;
    #pragma unroll
    for (int r = 0; r < BM; ++r) {
        const float* kp = &ldsK[r * LDK_STR + h * KSZ];
        v4f a = (v4f){0.f, 0.f, 0.f, 0.f};
        #pragma unroll
        for (int i = 0; i < KSZ; ++i) {
            a += kp[i] * win[r + i];
        }
        __builtin_nontemporal_store(a, (v4f*)(ob + (size_t)r * CH));
    }
}

extern "C" void kernel_launch(void* const* d_in, const int* in_sizes, int n_in,
                              void* d_out, int out_size, void* d_ws, size_t ws_size,
                              hipStream_t stream) {
    const float* x  = (const float*)d_in[0];
    const float* Wp = (const float*)d_in[1];
    const float* bp = (const float*)d_in[2];
    float* out = (float*)d_out;

    if (ws_size >= (size_t)WS_FRAG_BYTES) {
        __bf16* wsB = (__bf16*)d_ws;
        prep_w<<<dim3(448), dim3(256), 0, stream>>>(Wp, wsB);
        dynconv_fused<true><<<dim3(1024), dim3(NTHREADS), 0, stream>>>(x, Wp, bp, wsB, out);
    } else {
        dynconv_fused<false><<<dim3(1024), dim3(NTHREADS), 0, stream>>>(x, Wp, bp, nullptr, out);
    }
}